// Round 2
// baseline (190.833 us; speedup 1.0000x reference)
//
#include <hip/hip_runtime.h>

// Fixed shape: B=1, H=2048, W=3072. Window WC=14, taps idx=(3,7,10).
constexpr int Wd  = 3072;
constexpr int SEG = 1024;            // 3 segments per row
constexpr int WC  = 14;

// One block = one 1024-col segment of one row. 256 threads x 4 outputs.
// Stage segment+halo of x,z into LDS (8.4 KB), each thread pulls its halo
// span as aligned ds_read_b128 into registers, computes the 14-tap window
// once and slides it 3x, stores 6 coalesced float4 streams.
//
// LDS col mapping: local = col - (c0-16); w0 = c0 + 4t.
//   zbuf[k] = zs[4t+k]       -> z[w0 + k - 16], k in [0,20)
//   xbuf[k] = xs[4(t+1)+k]   -> x[w0 + k - 12], k in [0,28)
__global__ __launch_bounds__(256)
void color_restore_kernel(const float* __restrict__ xg,
                          const float* __restrict__ zg,
                          float* __restrict__ out, int Hn)
{
    __shared__ __align__(16) float xs[SEG + 32];  // cols [c0-16, c0+SEG+16)
    __shared__ __align__(16) float zs[SEG + 16];  // cols [c0-16, c0+SEG)

    const int p  = blockIdx.x;        // segment 0..2
    const int h  = blockIdx.y;        // row
    const int t  = threadIdx.x;
    const int c0 = p * SEG;

    const float4* xrow = (const float4*)(xg + (size_t)h * Wd);
    const float4* zrow = (const float4*)(zg + (size_t)h * Wd);
    float4* xs4 = (float4*)xs;
    float4* zs4 = (float4*)zs;
    const int b0 = c0 >> 2;           // segment base in float4 units

    // ---- stage: main body (coalesced) + masked halos ----
    xs4[4 + t] = xrow[b0 + t];
    zs4[4 + t] = zrow[b0 + t];
    const float4 zero4 = make_float4(0.f, 0.f, 0.f, 0.f);
    if (t < 4) {                      // x front halo (cols c0-16..c0-1)
        const int c4 = b0 - 4 + t;
        xs4[t] = (c4 >= 0) ? xrow[c4] : zero4;
    } else if (t < 8) {               // x tail halo (cols c0+SEG..+15; x==0 past W)
        const int i = t - 4, c4 = b0 + (SEG >> 2) + i;
        xs4[4 + (SEG >> 2) + i] = (c4 < (Wd >> 2)) ? xrow[c4] : zero4;
    } else if (t < 12) {              // z front halo (z==0 before col 0)
        const int i = t - 8, c4 = b0 - 4 + i;
        zs4[i] = (c4 >= 0) ? zrow[c4] : zero4;
    }
    __syncthreads();

    // ---- registers: halo spans via aligned ds_read_b128 ----
    float zbuf[20];
    {
        float4* zb = (float4*)zbuf;
#pragma unroll
        for (int i = 0; i < 5; ++i) zb[i] = zs4[t + i];
    }
    float xbuf[28];
    {
        float4* xb = (float4*)xbuf;
#pragma unroll
        for (int i = 0; i < 7; ++i) xb[i] = xs4[t + 1 + i];
    }

    // ---- initial 14-tap window at w = w0 ----
    float den = 0.f, n0 = 0.f, n1 = 0.f, n2 = 0.f;
#pragma unroll
    for (int s = 0; s < WC; ++s) {    // j = w0 - 13 + s
        const float zj = zbuf[3 + s];
        den += zj;
        n0 = fmaf(xbuf[s + 2], zj, n0);   // x[j+3]
        n1 = fmaf(xbuf[s + 6], zj, n1);   // x[j+7]
        n2 = fmaf(xbuf[s + 9], zj, n2);   // x[j+10]
    }

    float y0[4], y1[4], y2[4], r0[4], r1[4], r2[4];
#pragma unroll
    for (int q = 0; q < 4; ++q) {     // w = w0 + q
        if (q > 0) {
            const float zin = zbuf[16 + q];   // z[w]
            const float zot = zbuf[2 + q];    // z[w-14]
            den += zin - zot;
            n0 += xbuf[15 + q] * zin - xbuf[1 + q] * zot;  // x[w+3],  x[w-11]
            n1 += xbuf[19 + q] * zin - xbuf[5 + q] * zot;  // x[w+7],  x[w-7]
            n2 += xbuf[22 + q] * zin - xbuf[8 + q] * zot;  // x[w+10], x[w-4]
        }
        const float rinv = __builtin_amdgcn_rcpf(den);
        y0[q] = n0 * rinv;
        y1[q] = n1 * rinv;
        y2[q] = n2 * rinv;
        r0[q] = zbuf[13 + q];   // z[w-3]
        r1[q] = zbuf[9 + q];    // z[w-7]
        r2[q] = zbuf[6 + q];    // z[w-10]
    }

    // ---- coalesced float4 stores, 6 plane streams ----
    const int plane = Hn * Wd;
    float* yout = out;
    float* rout = out + 3 * (size_t)plane;
    const int off = h * Wd + c0 + 4 * t;
    *(float4*)(yout + off)             = make_float4(y0[0], y0[1], y0[2], y0[3]);
    *(float4*)(yout + plane + off)     = make_float4(y1[0], y1[1], y1[2], y1[3]);
    *(float4*)(yout + 2 * plane + off) = make_float4(y2[0], y2[1], y2[2], y2[3]);
    *(float4*)(rout + off)             = make_float4(r0[0], r0[1], r0[2], r0[3]);
    *(float4*)(rout + plane + off)     = make_float4(r1[0], r1[1], r1[2], r1[3]);
    *(float4*)(rout + 2 * plane + off) = make_float4(r2[0], r2[1], r2[2], r2[3]);
}

extern "C" void kernel_launch(void* const* d_in, const int* in_sizes, int n_in,
                              void* d_out, int out_size, void* d_ws, size_t ws_size,
                              hipStream_t stream)
{
    const float* x = (const float*)d_in[0];
    const float* z = (const float*)d_in[1];
    float* out = (float*)d_out;
    const int Hn = in_sizes[0] / Wd;   // 2048
    color_restore_kernel<<<dim3(3, Hn), dim3(256), 0, stream>>>(x, z, out, Hn);
}